// Round 1
// baseline (1211.491 us; speedup 1.0000x reference)
//
#include <hip/hip_runtime.h>

// GIN layer: out = relu(relu((x + scatter_sum(x[src]->dst)) @ W1^T + b1) @ W2^T + b2)
// N=100000 nodes, D=128 feats, E=625000 edges. All fp32 in/out.

#define D 128

typedef __attribute__((ext_vector_type(8))) short bf16x8;
typedef __attribute__((ext_vector_type(4))) float f32x4;

__device__ __forceinline__ short f2bf(float f) {
    union { float f; unsigned u; } v; v.f = f;
    unsigned r = v.u + 0x7fffu + ((v.u >> 16) & 1u);  // RNE
    return (short)(r >> 16);
}

// ---------------- k1: h0 = x ----------------
__global__ __launch_bounds__(256) void copy_f4(const float4* __restrict__ src,
                                               float4* __restrict__ dst, int n4) {
    int i = blockIdx.x * 256 + threadIdx.x;
    if (i < n4) dst[i] = src[i];
}

// ---------------- k2: h0[dst] += x[src] ----------------
// 32 lanes per edge; each lane: one float4 gather + 4 fp32 atomic adds.
__global__ __launch_bounds__(256) void scatter_add(const float4* __restrict__ x4,
                                                   const int* __restrict__ ei,
                                                   float* __restrict__ h0, int E) {
    int gid = blockIdx.x * 256 + threadIdx.x;
    int e = gid >> 5;
    if (e >= E) return;
    int l = gid & 31;
    int src = ei[e];
    int dst = ei[E + e];
    float4 v = x4[src * 32 + l];
    float* p = h0 + (long long)dst * D + l * 4;
    atomicAdd(p + 0, v.x);
    atomicAdd(p + 1, v.y);
    atomicAdd(p + 2, v.z);
    atomicAdd(p + 3, v.w);
}

// ---------------- k3/k4: out = relu(in @ W^T + b) ----------------
// Per block: 256 thr = 4 waves, 64 rows (16 rows/wave), full 128-col strip.
// W (row-major [j][k], i.e. B^T) staged to LDS as bf16, row-padded +8.
#define WLD 136  // 128 + 8 shorts padding -> 2-way max LDS aliasing (free)

template <bool IN_BF16, bool OUT_BF16>
__global__ __launch_bounds__(256) void gemm_bias_relu(const void* __restrict__ inp,
                                                      const float* __restrict__ W,
                                                      const float* __restrict__ bias,
                                                      void* __restrict__ outp, int N) {
    __shared__ short Wl[D * WLD];
    // stage W -> LDS (bf16), 128x128 = 4096 float4
    {
        const float4* W4 = (const float4*)W;
        for (int idx = threadIdx.x; idx < D * (D / 4); idx += 256) {
            int n = idx >> 5;       // row
            int k4 = idx & 31;      // float4 within row
            float4 w = W4[idx];
            short* d = &Wl[n * WLD + k4 * 4];
            d[0] = f2bf(w.x); d[1] = f2bf(w.y); d[2] = f2bf(w.z); d[3] = f2bf(w.w);
        }
    }
    __syncthreads();

    const int wave = threadIdx.x >> 6;
    const int lane = threadIdx.x & 63;
    const int m = lane & 15;
    const int quad = lane >> 4;
    const int r0 = blockIdx.x * 64 + wave * 16;
    const int arow = r0 + m;

    // A fragments: A[m=lane&15][k = quad*8 + j], 4 k-steps of 32
    bf16x8 afrag[4];
    if (arow < N) {
        if (IN_BF16) {
            const short* in = (const short*)inp;
#pragma unroll
            for (int ks = 0; ks < 4; ++ks)
                afrag[ks] = *(const bf16x8*)&in[(long long)arow * D + ks * 32 + quad * 8];
        } else {
            const float* in = (const float*)inp;
#pragma unroll
            for (int ks = 0; ks < 4; ++ks) {
                const float* p = &in[(long long)arow * D + ks * 32 + quad * 8];
                float4 u = *(const float4*)p;
                float4 v = *(const float4*)(p + 4);
                bf16x8 a;
                a[0] = f2bf(u.x); a[1] = f2bf(u.y); a[2] = f2bf(u.z); a[3] = f2bf(u.w);
                a[4] = f2bf(v.x); a[5] = f2bf(v.y); a[6] = f2bf(v.z); a[7] = f2bf(v.w);
                afrag[ks] = a;
            }
        }
    } else {
#pragma unroll
        for (int ks = 0; ks < 4; ++ks) afrag[ks] = (bf16x8)(short)0;
    }

    f32x4 acc[8];
#pragma unroll
    for (int jt = 0; jt < 8; ++jt) acc[jt] = (f32x4)0.0f;

#pragma unroll
    for (int jt = 0; jt < 8; ++jt) {
#pragma unroll
        for (int ks = 0; ks < 4; ++ks) {
            bf16x8 b = *(const bf16x8*)&Wl[(jt * 16 + m) * WLD + ks * 32 + quad * 8];
            acc[jt] = __builtin_amdgcn_mfma_f32_16x16x32_bf16(afrag[ks], b, acc[jt], 0, 0, 0);
        }
    }

    // epilogue: D layout col = lane&15, row = quad*4 + reg
#pragma unroll
    for (int jt = 0; jt < 8; ++jt) {
        int col = jt * 16 + m;
        float bv = bias[col];
#pragma unroll
        for (int i = 0; i < 4; ++i) {
            int row = r0 + quad * 4 + i;
            if (row < N) {
                float v = acc[jt][i] + bv;
                v = v > 0.0f ? v : 0.0f;
                if (OUT_BF16)
                    ((short*)outp)[(long long)row * D + col] = f2bf(v);
                else
                    ((float*)outp)[(long long)row * D + col] = v;
            }
        }
    }
}

extern "C" void kernel_launch(void* const* d_in, const int* in_sizes, int n_in,
                              void* d_out, int out_size, void* d_ws, size_t ws_size,
                              hipStream_t stream) {
    const float* x  = (const float*)d_in[0];
    const int*   ei = (const int*)d_in[1];
    const float* W1 = (const float*)d_in[2];
    const float* b1 = (const float*)d_in[3];
    const float* W2 = (const float*)d_in[4];
    const float* b2 = (const float*)d_in[5];
    float* out = (float*)d_out;

    const int N = in_sizes[0] / D;
    const int E = in_sizes[1] / 2;

    float* h0 = (float*)d_ws;              // N*D fp32 (51.2 MB)
    short* h1 = (short*)(h0 + (size_t)N * D);  // N*D bf16 (25.6 MB)

    // k1: h0 = x  (eps=0 -> (1+eps)*x = x)
    {
        int n4 = N * (D / 4);
        copy_f4<<<(n4 + 255) / 256, 256, 0, stream>>>((const float4*)x, (float4*)h0, n4);
    }
    // k2: scatter-add
    {
        long long thr = (long long)E * 32;
        int blocks = (int)((thr + 255) / 256);
        scatter_add<<<blocks, 256, 0, stream>>>((const float4*)x, ei, h0, E);
    }
    // k3: h1 = relu(h0 @ W1^T + b1), bf16 out
    {
        int blocks = (N + 63) / 64;
        gemm_bias_relu<false, true><<<blocks, 256, 0, stream>>>(h0, W1, b1, h1, N);
    }
    // k4: out = relu(h1 @ W2^T + b2), fp32 out
    {
        int blocks = (N + 63) / 64;
        gemm_bias_relu<true, false><<<blocks, 256, 0, stream>>>(h1, W2, b2, out, N);
    }
}

// Round 2
// 278.688 us; speedup vs baseline: 4.3471x; 4.3471x over previous
//
#include <hip/hip_runtime.h>

// GIN layer: out = relu(relu((x + scatter_sum(x[src]->dst)) @ W1^T + b1) @ W2^T + b2)
// N=100000 nodes, D=128 feats, E=625000 edges. All fp32 in/out.
//
// R2: replace 80M-fp32-atomic scatter (1052 us, atomic-RMW bound, WRITE_SIZE
// 1.25 GB) with counting-sort CSR + gather (1.25M int atomics + plain loads).

#define D 128

typedef __attribute__((ext_vector_type(8))) short bf16x8;
typedef __attribute__((ext_vector_type(4))) float f32x4;

__device__ __forceinline__ short f2bf(float f) {
    union { float f; unsigned u; } v; v.f = f;
    unsigned r = v.u + 0x7fffu + ((v.u >> 16) & 1u);  // RNE
    return (short)(r >> 16);
}

// ---------------- counting sort: hist -> scan -> fill ----------------

__global__ __launch_bounds__(256) void hist_kernel(const int* __restrict__ ei,
                                                   int* __restrict__ cnt, int E) {
    int e = blockIdx.x * 256 + threadIdx.x;
    if (e < E) atomicAdd(&cnt[ei[E + e]], 1);
}

#define SCAN_ELEMS 2048  // 256 thr x 8

__global__ __launch_bounds__(256) void scanA(const int* __restrict__ cnt,
                                             int* __restrict__ blkSum, int N) {
    __shared__ int red[256];
    int tid = threadIdx.x;
    int base = blockIdx.x * SCAN_ELEMS + tid * 8;
    int s = 0;
#pragma unroll
    for (int j = 0; j < 8; ++j) {
        int idx = base + j;
        s += (idx < N) ? cnt[idx] : 0;
    }
    red[tid] = s;
    __syncthreads();
    for (int o = 128; o > 0; o >>= 1) {
        if (tid < o) red[tid] += red[tid + o];
        __syncthreads();
    }
    if (tid == 0) blkSum[blockIdx.x] = red[0];
}

__global__ void scanB(const int* __restrict__ blkSum, int* __restrict__ blkOff,
                      int* __restrict__ off, int nb, int N) {
    if (threadIdx.x == 0) {
        int run = 0;
        for (int i = 0; i < nb; ++i) { blkOff[i] = run; run += blkSum[i]; }
        off[N] = run;  // total = E
    }
}

__global__ __launch_bounds__(256) void scanC(const int* __restrict__ cnt,
                                             const int* __restrict__ blkOff,
                                             int* __restrict__ off,
                                             int* __restrict__ cur, int N) {
    __shared__ int ls[256];
    int tid = threadIdx.x;
    int base = blockIdx.x * SCAN_ELEMS + tid * 8;
    int v[8];
    int t = 0;
#pragma unroll
    for (int j = 0; j < 8; ++j) {
        int idx = base + j;
        int c = (idx < N) ? cnt[idx] : 0;
        v[j] = t;  // exclusive within thread
        t += c;
    }
    ls[tid] = t;
    __syncthreads();
    // inclusive scan over thread totals
    for (int o = 1; o < 256; o <<= 1) {
        int add = (tid >= o) ? ls[tid - o] : 0;
        __syncthreads();
        ls[tid] += add;
        __syncthreads();
    }
    int texc = (tid ? ls[tid - 1] : 0) + blkOff[blockIdx.x];
#pragma unroll
    for (int j = 0; j < 8; ++j) {
        int idx = base + j;
        if (idx < N) {
            int val = texc + v[j];
            off[idx] = val;
            cur[idx] = val;
        }
    }
}

__global__ __launch_bounds__(256) void fill_kernel(const int* __restrict__ ei,
                                                   int* __restrict__ cur,
                                                   int* __restrict__ bucket, int E) {
    int e = blockIdx.x * 256 + threadIdx.x;
    if (e < E) {
        int dst = ei[E + e];
        int pos = atomicAdd(&cur[dst], 1);
        bucket[pos] = ei[e];  // src
    }
}

// ---------------- gather: h0[i] = x[i] + sum_{j in N(i)} x[j] ----------------
// 32 lanes per node, lane l owns float4 chunk l.
__global__ __launch_bounds__(256) void gather_kernel(const float4* __restrict__ x4,
                                                     const int* __restrict__ off,
                                                     const int* __restrict__ bucket,
                                                     float4* __restrict__ h04, int N) {
    int g = blockIdx.x * 256 + threadIdx.x;
    int node = g >> 5;
    if (node >= N) return;
    int lane = g & 31;
    int beg = off[node], end = off[node + 1];
    float4 acc = x4[node * 32 + lane];  // (1+eps)*x_i, eps=0
    int e = beg;
    for (; e + 1 < end; e += 2) {  // 2-deep for outstanding-load ILP
        int s0 = bucket[e], s1 = bucket[e + 1];
        float4 a = x4[s0 * 32 + lane];
        float4 b = x4[s1 * 32 + lane];
        acc.x += a.x; acc.y += a.y; acc.z += a.z; acc.w += a.w;
        acc.x += b.x; acc.y += b.y; acc.z += b.z; acc.w += b.w;
    }
    if (e < end) {
        int s0 = bucket[e];
        float4 a = x4[s0 * 32 + lane];
        acc.x += a.x; acc.y += a.y; acc.z += a.z; acc.w += a.w;
    }
    h04[node * 32 + lane] = acc;
}

// ---------------- GEMMs: out = relu(in @ W^T + b) ----------------
#define WLD 136  // 128 + 8 shorts padding -> 2-way max LDS aliasing (free)

template <bool IN_BF16, bool OUT_BF16>
__global__ __launch_bounds__(256) void gemm_bias_relu(const void* __restrict__ inp,
                                                      const float* __restrict__ W,
                                                      const float* __restrict__ bias,
                                                      void* __restrict__ outp, int N) {
    __shared__ short Wl[D * WLD];
    {
        const float4* W4 = (const float4*)W;
        for (int idx = threadIdx.x; idx < D * (D / 4); idx += 256) {
            int n = idx >> 5;
            int k4 = idx & 31;
            float4 w = W4[idx];
            short* d = &Wl[n * WLD + k4 * 4];
            d[0] = f2bf(w.x); d[1] = f2bf(w.y); d[2] = f2bf(w.z); d[3] = f2bf(w.w);
        }
    }
    __syncthreads();

    const int wave = threadIdx.x >> 6;
    const int lane = threadIdx.x & 63;
    const int m = lane & 15;
    const int quad = lane >> 4;
    const int r0 = blockIdx.x * 64 + wave * 16;
    const int arow = r0 + m;

    bf16x8 afrag[4];
    if (arow < N) {
        if (IN_BF16) {
            const short* in = (const short*)inp;
#pragma unroll
            for (int ks = 0; ks < 4; ++ks)
                afrag[ks] = *(const bf16x8*)&in[(long long)arow * D + ks * 32 + quad * 8];
        } else {
            const float* in = (const float*)inp;
#pragma unroll
            for (int ks = 0; ks < 4; ++ks) {
                const float* p = &in[(long long)arow * D + ks * 32 + quad * 8];
                float4 u = *(const float4*)p;
                float4 v = *(const float4*)(p + 4);
                bf16x8 a;
                a[0] = f2bf(u.x); a[1] = f2bf(u.y); a[2] = f2bf(u.z); a[3] = f2bf(u.w);
                a[4] = f2bf(v.x); a[5] = f2bf(v.y); a[6] = f2bf(v.z); a[7] = f2bf(v.w);
                afrag[ks] = a;
            }
        }
    } else {
#pragma unroll
        for (int ks = 0; ks < 4; ++ks) afrag[ks] = (bf16x8)(short)0;
    }

    f32x4 acc[8];
#pragma unroll
    for (int jt = 0; jt < 8; ++jt) acc[jt] = (f32x4)0.0f;

#pragma unroll
    for (int jt = 0; jt < 8; ++jt) {
#pragma unroll
        for (int ks = 0; ks < 4; ++ks) {
            bf16x8 b = *(const bf16x8*)&Wl[(jt * 16 + m) * WLD + ks * 32 + quad * 8];
            acc[jt] = __builtin_amdgcn_mfma_f32_16x16x32_bf16(afrag[ks], b, acc[jt], 0, 0, 0);
        }
    }

#pragma unroll
    for (int jt = 0; jt < 8; ++jt) {
        int col = jt * 16 + m;
        float bv = bias[col];
#pragma unroll
        for (int i = 0; i < 4; ++i) {
            int row = r0 + quad * 4 + i;
            if (row < N) {
                float v = acc[jt][i] + bv;
                v = v > 0.0f ? v : 0.0f;
                if (OUT_BF16)
                    ((short*)outp)[(long long)row * D + col] = f2bf(v);
                else
                    ((float*)outp)[(long long)row * D + col] = v;
            }
        }
    }
}

extern "C" void kernel_launch(void* const* d_in, const int* in_sizes, int n_in,
                              void* d_out, int out_size, void* d_ws, size_t ws_size,
                              hipStream_t stream) {
    const float* x  = (const float*)d_in[0];
    const int*   ei = (const int*)d_in[1];
    const float* W1 = (const float*)d_in[2];
    const float* b1 = (const float*)d_in[3];
    const float* W2 = (const float*)d_in[4];
    const float* b2 = (const float*)d_in[5];
    float* out = (float*)d_out;

    const int N = in_sizes[0] / D;
    const int E = in_sizes[1] / 2;

    // ws layout: [h0: N*D fp32 = 51.2MB][regionB: 25.6MB]
    // regionB holds CSR aux (cnt/off/cur/bucket/blkSum/blkOff ~3.7MB) until
    // gather completes, then is reused as h1 (N*D bf16). Total 76.8MB.
    float* h0 = (float*)d_ws;
    char* regionB = (char*)(h0 + (size_t)N * D);
    int* cnt    = (int*)regionB;        // N
    int* off    = cnt + N;              // N+1
    int* cur    = off + N + 1;          // N
    int* bucket = cur + N;              // E
    int* blkSum = bucket + E;           // <=64
    int* blkOff = blkSum + 64;          // <=64
    short* h1 = (short*)regionB;        // N*D bf16, aliases aux (used after gather)

    const int nScanBlks = (N + SCAN_ELEMS - 1) / SCAN_ELEMS;

    hipMemsetAsync(cnt, 0, (size_t)N * sizeof(int), stream);
    hist_kernel<<<(E + 255) / 256, 256, 0, stream>>>(ei, cnt, E);
    scanA<<<nScanBlks, 256, 0, stream>>>(cnt, blkSum, N);
    scanB<<<1, 64, 0, stream>>>(blkSum, blkOff, off, nScanBlks, N);
    scanC<<<nScanBlks, 256, 0, stream>>>(cnt, blkOff, off, cur, N);
    fill_kernel<<<(E + 255) / 256, 256, 0, stream>>>(ei, cur, bucket, E);

    {
        long long thr = (long long)N * 32;
        gather_kernel<<<(int)((thr + 255) / 256), 256, 0, stream>>>(
            (const float4*)x, off, bucket, (float4*)h0, N);
    }

    {
        int blocks = (N + 63) / 64;
        gemm_bias_relu<false, true><<<blocks, 256, 0, stream>>>(h0, W1, b1, h1, N);
        gemm_bias_relu<true, false><<<blocks, 256, 0, stream>>>(h1, W2, b2, out, N);
    }
}

// Round 3
// 262.548 us; speedup vs baseline: 4.6144x; 1.0615x over previous
//
#include <hip/hip_runtime.h>

// GIN layer: out = relu(relu((x + scatter_sum(x[src]->dst)) @ W1^T + b1) @ W2^T + b2)
// N=100000 nodes, D=128 feats, E=625000 edges. fp32 in/out.
//
// R2: CSR counting-sort + gather (1211 -> 279 us).
// R3: gather emits bf16 h0 (same rounding point as GEMM1's A-conversion);
//     GEMM1+GEMM2 fused in one kernel, h1 lives only in LDS (saves 102 MB
//     of h0/h1 round-trip traffic + 1 dispatch); gather 4-deep ILP.

#define D 128
#define HLD 136  // LDS row pitch (shorts): +8 pad -> <=2-way bank aliasing (free)

typedef __attribute__((ext_vector_type(8))) short bf16x8;
typedef __attribute__((ext_vector_type(4))) float f32x4;

__device__ __forceinline__ short f2bf(float f) {
    union { float f; unsigned u; } v; v.f = f;
    unsigned r = v.u + 0x7fffu + ((v.u >> 16) & 1u);  // RNE
    return (short)(r >> 16);
}

// ---------------- counting sort: hist -> scan -> fill ----------------

__global__ __launch_bounds__(256) void hist_kernel(const int* __restrict__ ei,
                                                   int* __restrict__ cnt, int E) {
    int e = blockIdx.x * 256 + threadIdx.x;
    if (e < E) atomicAdd(&cnt[ei[E + e]], 1);
}

#define SCAN_ELEMS 2048  // 256 thr x 8

__global__ __launch_bounds__(256) void scanA(const int* __restrict__ cnt,
                                             int* __restrict__ blkSum, int N) {
    __shared__ int red[256];
    int tid = threadIdx.x;
    int base = blockIdx.x * SCAN_ELEMS + tid * 8;
    int s = 0;
#pragma unroll
    for (int j = 0; j < 8; ++j) {
        int idx = base + j;
        s += (idx < N) ? cnt[idx] : 0;
    }
    red[tid] = s;
    __syncthreads();
    for (int o = 128; o > 0; o >>= 1) {
        if (tid < o) red[tid] += red[tid + o];
        __syncthreads();
    }
    if (tid == 0) blkSum[blockIdx.x] = red[0];
}

__global__ void scanB(const int* __restrict__ blkSum, int* __restrict__ blkOff,
                      int* __restrict__ off, int nb, int N) {
    if (threadIdx.x == 0) {
        int run = 0;
        for (int i = 0; i < nb; ++i) { blkOff[i] = run; run += blkSum[i]; }
        off[N] = run;  // total = E
    }
}

__global__ __launch_bounds__(256) void scanC(const int* __restrict__ cnt,
                                             const int* __restrict__ blkOff,
                                             int* __restrict__ off,
                                             int* __restrict__ cur, int N) {
    __shared__ int ls[256];
    int tid = threadIdx.x;
    int base = blockIdx.x * SCAN_ELEMS + tid * 8;
    int v[8];
    int t = 0;
#pragma unroll
    for (int j = 0; j < 8; ++j) {
        int idx = base + j;
        int c = (idx < N) ? cnt[idx] : 0;
        v[j] = t;
        t += c;
    }
    ls[tid] = t;
    __syncthreads();
    for (int o = 1; o < 256; o <<= 1) {
        int add = (tid >= o) ? ls[tid - o] : 0;
        __syncthreads();
        ls[tid] += add;
        __syncthreads();
    }
    int texc = (tid ? ls[tid - 1] : 0) + blkOff[blockIdx.x];
#pragma unroll
    for (int j = 0; j < 8; ++j) {
        int idx = base + j;
        if (idx < N) {
            int val = texc + v[j];
            off[idx] = val;
            cur[idx] = val;
        }
    }
}

__global__ __launch_bounds__(256) void fill_kernel(const int* __restrict__ ei,
                                                   int* __restrict__ cur,
                                                   int* __restrict__ bucket, int E) {
    int e = blockIdx.x * 256 + threadIdx.x;
    if (e < E) {
        int dst = ei[E + e];
        int pos = atomicAdd(&cur[dst], 1);
        bucket[pos] = ei[e];  // src
    }
}

// ---------------- gather: h0[i] = bf16(x[i] + sum_{j in N(i)} x[j]) ----------
// 32 lanes per node, lane l owns float4 chunk l. 4-deep unroll for MLP of
// outstanding loads (R2 counters: VALUBusy 10%, latency-bound).
__global__ __launch_bounds__(256) void gather_kernel(const float4* __restrict__ x4,
                                                     const int* __restrict__ off,
                                                     const int* __restrict__ bucket,
                                                     short* __restrict__ h0, int N) {
    int g = blockIdx.x * 256 + threadIdx.x;
    int node = g >> 5;
    if (node >= N) return;
    int lane = g & 31;
    int beg = off[node], end = off[node + 1];
    float4 acc = x4[node * 32 + lane];  // (1+eps)*x_i, eps=0
    int e = beg;
    for (; e + 3 < end; e += 4) {
        int s0 = bucket[e], s1 = bucket[e + 1], s2 = bucket[e + 2], s3 = bucket[e + 3];
        float4 a = x4[s0 * 32 + lane];
        float4 b = x4[s1 * 32 + lane];
        float4 c = x4[s2 * 32 + lane];
        float4 d = x4[s3 * 32 + lane];
        acc.x += a.x + b.x + c.x + d.x;
        acc.y += a.y + b.y + c.y + d.y;
        acc.z += a.z + b.z + c.z + d.z;
        acc.w += a.w + b.w + c.w + d.w;
    }
    for (; e < end; ++e) {
        int s0 = bucket[e];
        float4 a = x4[s0 * 32 + lane];
        acc.x += a.x; acc.y += a.y; acc.z += a.z; acc.w += a.w;
    }
    short4 r;
    r.x = f2bf(acc.x); r.y = f2bf(acc.y); r.z = f2bf(acc.z); r.w = f2bf(acc.w);
    ((short4*)h0)[node * 32 + lane] = r;
}

// ---------------- fused MLP: out = relu(relu(h0 @ W1^T + b1) @ W2^T + b2) ----
// 512 thr = 8 waves, 128 rows/block (16 rows/wave). W1,W2 bf16 in LDS.
// h1 tile lives only in LDS: GEMM1 C-layout (col=lane&15,row=quad*4+reg) is
// written to h1l, re-read in A-layout (A[m=lane&15][k=quad*8+j]). Each wave
// writes/reads only its own 16 rows -> no barrier needed between the GEMMs
// (within-wave ds ordering via lgkmcnt is enough).
__global__ __launch_bounds__(512) void mlp_fused(const short* __restrict__ h0,
                                                 const float* __restrict__ W1,
                                                 const float* __restrict__ b1,
                                                 const float* __restrict__ W2,
                                                 const float* __restrict__ b2,
                                                 float* __restrict__ out, int N) {
    __shared__ short W1l[D * HLD];   // 34816 B
    __shared__ short W2l[D * HLD];   // 34816 B
    __shared__ short h1l[D * HLD];   // 34816 B (128 tile rows)

    {
        const float4* W14 = (const float4*)W1;
        const float4* W24 = (const float4*)W2;
        for (int idx = threadIdx.x; idx < D * (D / 4); idx += 512) {
            int n = idx >> 5;
            int k4 = idx & 31;
            float4 w = W14[idx];
            short* dp = &W1l[n * HLD + k4 * 4];
            dp[0] = f2bf(w.x); dp[1] = f2bf(w.y); dp[2] = f2bf(w.z); dp[3] = f2bf(w.w);
            w = W24[idx];
            dp = &W2l[n * HLD + k4 * 4];
            dp[0] = f2bf(w.x); dp[1] = f2bf(w.y); dp[2] = f2bf(w.z); dp[3] = f2bf(w.w);
        }
    }
    __syncthreads();

    const int wave = threadIdx.x >> 6;   // 0..7
    const int lane = threadIdx.x & 63;
    const int m = lane & 15;
    const int quad = lane >> 4;
    const int r0 = blockIdx.x * 128 + wave * 16;
    const int arow = r0 + m;

    // A fragments from global bf16 h0 (no conversion needed)
    bf16x8 afrag[4];
    if (arow < N) {
#pragma unroll
        for (int ks = 0; ks < 4; ++ks)
            afrag[ks] = *(const bf16x8*)&h0[(long long)arow * D + ks * 32 + quad * 8];
    } else {
#pragma unroll
        for (int ks = 0; ks < 4; ++ks) afrag[ks] = (bf16x8)(short)0;
    }

    // GEMM1
    f32x4 acc[8];
#pragma unroll
    for (int jt = 0; jt < 8; ++jt) acc[jt] = (f32x4)0.0f;
#pragma unroll
    for (int jt = 0; jt < 8; ++jt) {
#pragma unroll
        for (int ks = 0; ks < 4; ++ks) {
            bf16x8 b = *(const bf16x8*)&W1l[(jt * 16 + m) * HLD + ks * 32 + quad * 8];
            acc[jt] = __builtin_amdgcn_mfma_f32_16x16x32_bf16(afrag[ks], b, acc[jt], 0, 0, 0);
        }
    }

    // bias1 + relu -> h1l (wave-private rows wave*16 .. wave*16+15)
#pragma unroll
    for (int jt = 0; jt < 8; ++jt) {
        int col = jt * 16 + m;
        float bv = b1[col];
#pragma unroll
        for (int i = 0; i < 4; ++i) {
            float v = acc[jt][i] + bv;
            v = v > 0.0f ? v : 0.0f;
            h1l[(wave * 16 + quad * 4 + i) * HLD + col] = f2bf(v);
        }
    }

    // re-read in A layout (same wave's rows; lgkmcnt ordering suffices)
    bf16x8 a2[4];
#pragma unroll
    for (int ks = 0; ks < 4; ++ks)
        a2[ks] = *(const bf16x8*)&h1l[(wave * 16 + m) * HLD + ks * 32 + quad * 8];

    // GEMM2
    f32x4 acc2[8];
#pragma unroll
    for (int jt = 0; jt < 8; ++jt) acc2[jt] = (f32x4)0.0f;
#pragma unroll
    for (int jt = 0; jt < 8; ++jt) {
#pragma unroll
        for (int ks = 0; ks < 4; ++ks) {
            bf16x8 b = *(const bf16x8*)&W2l[(jt * 16 + m) * HLD + ks * 32 + quad * 8];
            acc2[jt] = __builtin_amdgcn_mfma_f32_16x16x32_bf16(a2[ks], b, acc2[jt], 0, 0, 0);
        }
    }

    // bias2 + relu -> out (fp32)
#pragma unroll
    for (int jt = 0; jt < 8; ++jt) {
        int col = jt * 16 + m;
        float bv = b2[col];
#pragma unroll
        for (int i = 0; i < 4; ++i) {
            int row = r0 + quad * 4 + i;
            if (row < N) {
                float v = acc2[jt][i] + bv;
                v = v > 0.0f ? v : 0.0f;
                out[(long long)row * D + col] = v;
            }
        }
    }
}

extern "C" void kernel_launch(void* const* d_in, const int* in_sizes, int n_in,
                              void* d_out, int out_size, void* d_ws, size_t ws_size,
                              hipStream_t stream) {
    const float* x  = (const float*)d_in[0];
    const int*   ei = (const int*)d_in[1];
    const float* W1 = (const float*)d_in[2];
    const float* b1 = (const float*)d_in[3];
    const float* W2 = (const float*)d_in[4];
    const float* b2 = (const float*)d_in[5];
    float* out = (float*)d_out;

    const int N = in_sizes[0] / D;
    const int E = in_sizes[1] / 2;

    // ws: [h0 bf16 N*D = 25.6MB][cnt N][off N+1][cur N][bucket E][blkSum][blkOff]
    short* h0 = (short*)d_ws;
    int* cnt    = (int*)(h0 + (size_t)N * D);
    int* off    = cnt + N;
    int* cur    = off + N + 1;
    int* bucket = cur + N;
    int* blkSum = bucket + E;
    int* blkOff = blkSum + 64;

    const int nScanBlks = (N + SCAN_ELEMS - 1) / SCAN_ELEMS;

    hipMemsetAsync(cnt, 0, (size_t)N * sizeof(int), stream);
    hist_kernel<<<(E + 255) / 256, 256, 0, stream>>>(ei, cnt, E);
    scanA<<<nScanBlks, 256, 0, stream>>>(cnt, blkSum, N);
    scanB<<<1, 64, 0, stream>>>(blkSum, blkOff, off, nScanBlks, N);
    scanC<<<nScanBlks, 256, 0, stream>>>(cnt, blkOff, off, cur, N);
    fill_kernel<<<(E + 255) / 256, 256, 0, stream>>>(ei, cur, bucket, E);

    {
        long long thr = (long long)N * 32;
        gather_kernel<<<(int)((thr + 255) / 256), 256, 0, stream>>>(
            (const float4*)x, off, bucket, h0, N);
    }

    mlp_fused<<<(N + 127) / 128, 512, 0, stream>>>(h0, W1, b1, W2, b2, out, N);
}